// Round 2
// baseline (343.899 us; speedup 1.0000x reference)
//
#include <hip/hip_runtime.h>
#include <math.h>

// Problem constants
#define NQ 8192          // points per batch
#define H_IN 384
#define W_IN 512
#define HH0 96           // conv out H
#define WW0 128          // conv out W
#define HH1 32           // pooled H
#define WW1 42           // pooled W

// ---------------------------------------------------------------------------
// Kernel 1: transpose conv weights (128,3,7,7) -> wT[tap][oc]
// ---------------------------------------------------------------------------
__global__ void transpose_w_kernel(const float* __restrict__ w, float* __restrict__ wT) {
    int idx = blockIdx.x * 256 + threadIdx.x;
    if (idx < 147 * 128) {
        int tap = idx >> 7;
        int oc  = idx & 127;
        wT[idx] = w[oc * 147 + tap];
    }
}

// ---------------------------------------------------------------------------
// Kernel 2: conv 7x7 stride 4 pad 3 + bias + relu, channels-last output
// ---------------------------------------------------------------------------
__global__ __launch_bounds__(256) void conv_kernel(
    const float* __restrict__ frames, const float* __restrict__ wT,
    const float* __restrict__ bias, float* __restrict__ out)
{
    __shared__ float lds[3 * 7 * 260];
    const int bs  = blockIdx.z;
    const int oh  = blockIdx.y;
    const int ow0 = blockIdx.x * 64;
    const int tid = threadIdx.x;

    for (int idx = tid; idx < 3 * 7 * 259; idx += 256) {
        int c   = idx / 1813;
        int rem = idx - c * 1813;
        int kh  = rem / 259;
        int col = rem - kh * 259;
        int gy  = oh * 4 - 3 + kh;
        int gx  = ow0 * 4 - 3 + col;
        float v = 0.0f;
        if (gy >= 0 && gy < H_IN && gx >= 0 && gx < W_IN) {
            float t = frames[((size_t)(bs * 3 + c) * H_IN + gy) * W_IN + gx];
            v = 2.0f * (t / 255.0f) - 1.0f;
        }
        lds[c * 1820 + kh * 260 + col] = v;
    }
    __syncthreads();

    const int oc = tid & 63;
    const int g  = tid >> 6;
    float a0[16], a1[16];
#pragma unroll
    for (int p = 0; p < 16; ++p) { a0[p] = 0.0f; a1[p] = 0.0f; }

#pragma unroll
    for (int c = 0; c < 3; ++c) {
#pragma unroll
        for (int kh = 0; kh < 7; ++kh) {
            const float* row = lds + c * 1820 + kh * 260 + g * 64;
            float w0[7], w1v[7];
#pragma unroll
            for (int kw = 0; kw < 7; ++kw) {
                int tap = (c * 7 + kh) * 7 + kw;
                w0[kw]  = wT[tap * 128 + oc];
                w1v[kw] = wT[tap * 128 + oc + 64];
            }
#pragma unroll
            for (int p = 0; p < 16; ++p) {
                const float4 A  = *(const float4*)(row + p * 4);
                const float4 Bv = *(const float4*)(row + p * 4 + 4);
                float s0 = a0[p], s1 = a1[p];
                s0 = fmaf(A.x,  w0[0], s0);  s1 = fmaf(A.x,  w1v[0], s1);
                s0 = fmaf(A.y,  w0[1], s0);  s1 = fmaf(A.y,  w1v[1], s1);
                s0 = fmaf(A.z,  w0[2], s0);  s1 = fmaf(A.z,  w1v[2], s1);
                s0 = fmaf(A.w,  w0[3], s0);  s1 = fmaf(A.w,  w1v[3], s1);
                s0 = fmaf(Bv.x, w0[4], s0);  s1 = fmaf(Bv.x, w1v[4], s1);
                s0 = fmaf(Bv.y, w0[5], s0);  s1 = fmaf(Bv.y, w1v[5], s1);
                s0 = fmaf(Bv.z, w0[6], s0);  s1 = fmaf(Bv.z, w1v[6], s1);
                a0[p] = s0; a1[p] = s1;
            }
        }
    }

    const float b0  = bias[oc];
    const float b1b = bias[oc + 64];
#pragma unroll
    for (int p = 0; p < 16; ++p) {
        int ow = ow0 + g * 16 + p;
        size_t ob = ((size_t)(bs * HH0 + oh) * WW0 + ow) * 128;
        out[ob + oc]      = fmaxf(a0[p] + b0, 0.0f);
        out[ob + oc + 64] = fmaxf(a1[p] + b1b, 0.0f);
    }
}

// ---------------------------------------------------------------------------
// Kernel 3: 3x3/s3 avg pool, channels-last
// ---------------------------------------------------------------------------
__global__ void pool_kernel(const float* __restrict__ in, float* __restrict__ out) {
    int idx = blockIdx.x * 256 + threadIdx.x;
    if (idx >= 4 * HH1 * WW1 * 128) return;
    int c = idx & 127;
    int r = idx >> 7;
    int px = r % WW1; r /= WW1;
    int py = r % HH1;
    int bs = r / HH1;
    float s = 0.0f;
#pragma unroll
    for (int dy = 0; dy < 3; ++dy)
#pragma unroll
        for (int dx = 0; dx < 3; ++dx)
            s += in[(((size_t)bs * HH0 + py * 3 + dy) * WW0 + px * 3 + dx) * 128 + c];
    out[idx] = s / 9.0f;
}

// ---------------------------------------------------------------------------
// gather one map: 4x4 float2 patch -> 9 bilinear window samples into LDS row
// ---------------------------------------------------------------------------
__device__ __forceinline__ void gather_map(const float2* __restrict__ src,
    const int* __restrict__ pix, const float* __restrict__ cwx,
    const float* __restrict__ cwy, int lane, float* __restrict__ dst)
{
    float2 P[4][4];
#pragma unroll
    for (int j = 0; j < 4; ++j)
#pragma unroll
        for (int i = 0; i < 4; ++i) P[j][i] = src[pix[j * 4 + i]];
#pragma unroll
    for (int ky = 0; ky < 3; ++ky)
#pragma unroll
        for (int kx = 0; kx < 3; ++kx) {
            float wA = cwy[ky * 2 + 0] * cwx[kx * 2 + 0];
            float wB = cwy[ky * 2 + 0] * cwx[kx * 2 + 1];
            float wC = cwy[ky * 2 + 1] * cwx[kx * 2 + 0];
            float wD = cwy[ky * 2 + 1] * cwx[kx * 2 + 1];
            float sx = wA * P[ky][kx].x;
            sx = fmaf(wB, P[ky][kx + 1].x, sx);
            sx = fmaf(wC, P[ky + 1][kx].x, sx);
            sx = fmaf(wD, P[ky + 1][kx + 1].x, sx);
            float sy = wA * P[ky][kx].y;
            sy = fmaf(wB, P[ky][kx + 1].y, sy);
            sy = fmaf(wC, P[ky + 1][kx].y, sy);
            sy = fmaf(wD, P[ky + 1][kx + 1].y, sy);
            *(float2*)(dst + (ky * 3 + kx) * 132 + 2 * lane) = make_float2(sx, sy);
        }
}

// ---------------------------------------------------------------------------
// Kernel 4: sample+corr. One wave per point. Writes corr[p][81] to global.
// ---------------------------------------------------------------------------
__global__ __launch_bounds__(256) void sample_kernel(
    const float* __restrict__ fm, int hh, int ww,
    const float* __restrict__ cur_in, float* __restrict__ corr_out)
{
    __shared__ float smem[4 * 2400];
    const int tid  = threadIdx.x;
    const int wvi  = tid >> 6;
    const int lane = tid & 63;
    const int p    = blockIdx.x * 4 + wvi;     // global point id
    const int b    = p >> 13;

    float* fl     = smem + wvi * 2400;         // [9][132]
    float* ml     = fl + 1188;                 // [9][132]
    float* invf_s = fl + 2376;                 // [9]
    float* invm_s = fl + 2385;                 // [9]

    const float2 pxy = *(const float2*)(cur_in + (size_t)p * 2);
    const float wwm1 = (float)(ww - 1);
    const float hhm1 = (float)(hh - 1);
    // center sample coords (exact reference formula for the dx=0/dy=0 tap)
    const float ix = ((pxy.x * 2.0f - 1.0f) + 1.0f) * 0.5f * wwm1;
    const float iy = ((pxy.y * 2.0f - 1.0f) + 1.0f) * 0.5f * hhm1;
    const float x0 = floorf(ix), y0 = floorf(iy);
    const float fx1 = ix - x0, fx0 = 1.0f - fx1;
    const float fy1 = iy - y0, fy0 = 1.0f - fy1;

    int   cx[4], cy[4];
    float vx[4], vy[4];
#pragma unroll
    for (int j = 0; j < 4; ++j) {
        float xc = x0 + (float)(j - 1);
        vx[j] = (xc >= 0.0f && xc <= wwm1) ? 1.0f : 0.0f;
        cx[j] = (int)fminf(fmaxf(xc, 0.0f), wwm1);
        float yc = y0 + (float)(j - 1);
        vy[j] = (yc >= 0.0f && yc <= hhm1) ? 1.0f : 0.0f;
        cy[j] = (int)fminf(fmaxf(yc, 0.0f), hhm1);
    }
    float cwx[6], cwy[6];
#pragma unroll
    for (int t = 0; t < 3; ++t) {
        cwx[t * 2 + 0] = fx0 * vx[t]; cwx[t * 2 + 1] = fx1 * vx[t + 1];
        cwy[t * 2 + 0] = fy0 * vy[t]; cwy[t * 2 + 1] = fy1 * vy[t + 1];
    }
    int pix[16];
#pragma unroll
    for (int j = 0; j < 4; ++j)
#pragma unroll
        for (int i = 0; i < 4; ++i)
            pix[j * 4 + i] = (cy[j] * ww + cx[i]) * 64 + lane;   // float2 units

    const float2* f0p = (const float2*)fm + (size_t)(b * 2 + 0) * hh * ww * 64;
    const float2* f1p = (const float2*)fm + (size_t)(b * 2 + 1) * hh * ww * 64;

    gather_map(f0p, pix, cwx, cwy, lane, fl);
    gather_map(f1p, pix, cwx, cwy, lane, ml);

    // dots: e<81 -> corr(h=e/9, k=e%9); 81..89 -> f.f; 90..98 -> m.m
    float sdot[2];
#pragma unroll
    for (int rep = 0; rep < 2; ++rep) {
        int e = lane + rep * 64;
        const float *rA, *rB;
        if (e < 81)      { rA = fl + (e / 9) * 132; rB = ml + (e % 9) * 132; }
        else if (e < 90) { rA = fl + (e - 81) * 132; rB = rA; }
        else             { int em = e - 90; if (em > 8) em = 8;
                           rA = ml + em * 132; rB = rA; }
        float s = 0.0f;
#pragma unroll
        for (int c = 0; c < 128; c += 4) {
            float4 a  = *(const float4*)(rA + c);
            float4 bb = *(const float4*)(rB + c);
            s += a.x * bb.x; s += a.y * bb.y; s += a.z * bb.z; s += a.w * bb.w;
        }
        sdot[rep] = s;
    }

    {
        int e1 = lane + 64;
        if (e1 >= 81 && e1 < 90)
            invf_s[e1 - 81] = 1.0f / fmaxf(sqrtf(sdot[1]), 1e-12f);
        else if (e1 >= 90 && e1 < 99)
            invm_s[e1 - 90] = 1.0f / fmaxf(sqrtf(sdot[1]), 1e-12f);
    }
    // same-wave LDS RAW: compiler inserts lgkmcnt
    corr_out[(size_t)p * 81 + lane] = sdot[0] * invf_s[lane / 9] * invm_s[lane % 9];
    int e1 = lane + 64;
    if (e1 < 81)
        corr_out[(size_t)p * 81 + e1] = sdot[1] * invf_s[e1 / 9] * invm_s[e1 % 9];
}

// ---------------------------------------------------------------------------
// Kernel 5: MLP + head. 64 points per block, lane = point, wave = j-slice.
// ---------------------------------------------------------------------------
__global__ __launch_bounds__(256) void mlp_kernel(
    const float* __restrict__ corr, const float* __restrict__ cur_in,
    const float* __restrict__ w1, const float* __restrict__ b1,
    const float* __restrict__ wp, const float* __restrict__ bp,
    const float* __restrict__ wvw, const float* __restrict__ bvv,
    int hh, int ww,
    float* __restrict__ cur_out,
    const float* __restrict__ vis_in, float* __restrict__ vis_out,
    int is_last)
{
    __shared__ float w1s[27 * 256];   // 27-row chunk of w1 (reused for wp|wv)
    __shared__ float cls[81 * 64];    // corr tile transposed [i][pt]
    __shared__ float red[4 * 10 * 64];
    const int tid  = threadIdx.x;
    const int wvi  = tid >> 6;
    const int lane = tid & 63;
    const int pbase = blockIdx.x * 64;
    const int jbase = wvi << 6;

    for (int idx = tid; idx < 81 * 64; idx += 256) {
        int i = idx >> 6, pt = idx & 63;
        cls[idx] = corr[(size_t)(pbase + pt) * 81 + i];
    }

    float h[64];
#pragma unroll
    for (int jj = 0; jj < 64; ++jj) h[jj] = b1[jbase + jj];

    for (int ch = 0; ch < 3; ++ch) {
        if (ch) __syncthreads();
        for (int idx = tid; idx < 27 * 256; idx += 256)
            w1s[idx] = w1[ch * 27 * 256 + idx];
        __syncthreads();
        for (int i = 0; i < 27; ++i) {
            float cv = cls[(ch * 27 + i) * 64 + lane];
#pragma unroll
            for (int q = 0; q < 16; ++q) {
                float4 wv4 = *(const float4*)(w1s + i * 256 + jbase + q * 4);
                h[q * 4 + 0] = fmaf(cv, wv4.x, h[q * 4 + 0]);
                h[q * 4 + 1] = fmaf(cv, wv4.y, h[q * 4 + 1]);
                h[q * 4 + 2] = fmaf(cv, wv4.z, h[q * 4 + 2]);
                h[q * 4 + 3] = fmaf(cv, wv4.w, h[q * 4 + 3]);
            }
        }
    }

    __syncthreads();
    for (int idx = tid; idx < 2304 + 256; idx += 256)
        w1s[idx] = (idx < 2304) ? wp[idx] : wvw[idx - 2304];
    __syncthreads();

    float pl[10];
#pragma unroll
    for (int o = 0; o < 10; ++o) pl[o] = 0.0f;
#pragma unroll
    for (int jj = 0; jj < 64; ++jj) {
        float hv = fmaxf(h[jj], 0.0f);
        const float* wr = w1s + (jbase + jj) * 9;
#pragma unroll
        for (int o = 0; o < 9; ++o) pl[o] = fmaf(hv, wr[o], pl[o]);
        pl[9] = fmaf(hv, w1s[2304 + jbase + jj], pl[9]);
    }
#pragma unroll
    for (int o = 0; o < 10; ++o) red[(wvi * 10 + o) * 64 + lane] = pl[o];
    __syncthreads();

    if (wvi == 0) {
        float fo[10];
#pragma unroll
        for (int o = 0; o < 10; ++o) {
            float v = red[o * 64 + lane];
            v += red[(10 + o) * 64 + lane];
            v += red[(20 + o) * 64 + lane];
            v += red[(30 + o) * 64 + lane];
            fo[o] = v;
        }
        const int p = pbase + lane;
        float lg[9];
#pragma unroll
        for (int o = 0; o < 9; ++o) lg[o] = fo[o] + bp[o];
        float mx = lg[0];
#pragma unroll
        for (int o = 1; o < 9; ++o) mx = fmaxf(mx, lg[o]);
        float ex[9], sum = 0.0f;
#pragma unroll
        for (int o = 0; o < 9; ++o) { ex[o] = expf(lg[o] - mx); sum += ex[o]; }
#pragma unroll
        for (int o = 0; o < 9; ++o) ex[o] = ex[o] / sum;

        float vis = 1.0f / (1.0f + expf(-(fo[9] + bvv[0])));

        const float wwm1 = (float)(ww - 1);
        const float hhm1 = (float)(hh - 1);
        const float ax = 1.0f / wwm1;
        const float ay = 1.0f / hhm1;
        float r0 = ex[0] + ex[1] + ex[2];
        float r1 = ex[3] + ex[4] + ex[5];
        float r2 = ex[6] + ex[7] + ex[8];
        float c0 = ex[0] + ex[3] + ex[6];
        float c1 = ex[1] + ex[4] + ex[7];
        float c2 = ex[2] + ex[5] + ex[8];
        float dx = r0 * (-ax) + r1 * 0.0f + r2 * ax;
        float dy = c0 * (-ay) + c1 * 0.0f + c2 * ay;

        float2 pq = *(const float2*)(cur_in + (size_t)p * 2);
        *(float2*)(cur_out + (size_t)p * 2) = make_float2(pq.x + dx, pq.y + dy);
        vis_out[p] = is_last ? (vis_in[p] + vis) * 0.5f : vis;
    }
}

// ---------------------------------------------------------------------------
extern "C" void kernel_launch(void* const* d_in, const int* in_sizes, int n_in,
                              void* d_out, int out_size, void* d_ws, size_t ws_size,
                              hipStream_t stream) {
    (void)in_sizes; (void)n_in; (void)out_size; (void)ws_size;
    const float* queries = (const float*)d_in[0];
    const float* frames  = (const float*)d_in[1];
    const float* conv_w  = (const float*)d_in[2];
    const float* conv_b  = (const float*)d_in[3];
    const float* w1      = (const float*)d_in[4];
    const float* b1      = (const float*)d_in[5];
    const float* wp      = (const float*)d_in[6];
    const float* bp      = (const float*)d_in[7];
    const float* wvw     = (const float*)d_in[8];
    const float* bvv     = (const float*)d_in[9];
    float* out = (float*)d_out;

    // ws layout (floats): fm0 | fm1 | wT | cur_ws | vis_ws | corrws (~33.5 MB)
    float* ws     = (float*)d_ws;
    float* fm0    = ws;                         // 6291456
    float* fm1    = fm0 + 6291456;              // 688128
    float* wT     = fm1 + 688128;               // 18816
    float* cur_ws = wT + 18816;                 // 32768
    float* vis_ws = cur_ws + 32768;             // 16384
    float* corrws = vis_ws + 16384;             // 16384*81 = 1327104

    transpose_w_kernel<<<74, 256, 0, stream>>>(conv_w, wT);
    conv_kernel<<<dim3(2, HH0, 4), 256, 0, stream>>>(frames, wT, conv_b, fm0);
    pool_kernel<<<2688, 256, 0, stream>>>(fm0, fm1);

    // level 0: coarse map
    sample_kernel<<<4096, 256, 0, stream>>>(fm1, HH1, WW1, queries, corrws);
    mlp_kernel<<<256, 256, 0, stream>>>(corrws, queries, w1, b1, wp, bp, wvw, bvv,
                                        HH1, WW1, cur_ws, nullptr, vis_ws, 0);
    // level 1: fine map, final outputs
    sample_kernel<<<4096, 256, 0, stream>>>(fm0, HH0, WW0, cur_ws, corrws);
    mlp_kernel<<<256, 256, 0, stream>>>(corrws, cur_ws, w1, b1, wp, bp, wvw, bvv,
                                        HH0, WW0, out, vis_ws, out + 32768, 1);
}

// Round 3
// 269.592 us; speedup vs baseline: 1.2756x; 1.2756x over previous
//
#include <hip/hip_runtime.h>
#include <math.h>

// Problem constants
#define NQ 8192          // points per batch
#define NP 16384         // total points (B*NQ)
#define H_IN 384
#define W_IN 512
#define HH0 96           // conv out H
#define WW0 128          // conv out W
#define HH1 32           // pooled H
#define WW1 42           // pooled W

// ---------------------------------------------------------------------------
// Kernel 1: transpose conv weights (128,3,7,7) -> wT[tap][oc]
// ---------------------------------------------------------------------------
__global__ void transpose_w_kernel(const float* __restrict__ w, float* __restrict__ wT) {
    int idx = blockIdx.x * 256 + threadIdx.x;
    if (idx < 147 * 128) {
        int tap = idx >> 7;
        int oc  = idx & 127;
        wT[idx] = w[oc * 147 + tap];
    }
}

// ---------------------------------------------------------------------------
// Kernel 2: conv 7x7 stride 4 pad 3 + bias + relu, channels-last output
// ---------------------------------------------------------------------------
__global__ __launch_bounds__(256) void conv_kernel(
    const float* __restrict__ frames, const float* __restrict__ wT,
    const float* __restrict__ bias, float* __restrict__ out)
{
    __shared__ float lds[3 * 7 * 260];
    const int bs  = blockIdx.z;
    const int oh  = blockIdx.y;
    const int ow0 = blockIdx.x * 64;
    const int tid = threadIdx.x;

    for (int idx = tid; idx < 3 * 7 * 259; idx += 256) {
        int c   = idx / 1813;
        int rem = idx - c * 1813;
        int kh  = rem / 259;
        int col = rem - kh * 259;
        int gy  = oh * 4 - 3 + kh;
        int gx  = ow0 * 4 - 3 + col;
        float v = 0.0f;
        if (gy >= 0 && gy < H_IN && gx >= 0 && gx < W_IN) {
            float t = frames[((size_t)(bs * 3 + c) * H_IN + gy) * W_IN + gx];
            v = 2.0f * (t / 255.0f) - 1.0f;
        }
        lds[c * 1820 + kh * 260 + col] = v;
    }
    __syncthreads();

    const int oc = tid & 63;
    const int g  = tid >> 6;
    float a0[16], a1[16];
#pragma unroll
    for (int p = 0; p < 16; ++p) { a0[p] = 0.0f; a1[p] = 0.0f; }

#pragma unroll
    for (int c = 0; c < 3; ++c) {
#pragma unroll
        for (int kh = 0; kh < 7; ++kh) {
            const float* row = lds + c * 1820 + kh * 260 + g * 64;
            float w0[7], w1v[7];
#pragma unroll
            for (int kw = 0; kw < 7; ++kw) {
                int tap = (c * 7 + kh) * 7 + kw;
                w0[kw]  = wT[tap * 128 + oc];
                w1v[kw] = wT[tap * 128 + oc + 64];
            }
#pragma unroll
            for (int p = 0; p < 16; ++p) {
                const float4 A  = *(const float4*)(row + p * 4);
                const float4 Bv = *(const float4*)(row + p * 4 + 4);
                float s0 = a0[p], s1 = a1[p];
                s0 = fmaf(A.x,  w0[0], s0);  s1 = fmaf(A.x,  w1v[0], s1);
                s0 = fmaf(A.y,  w0[1], s0);  s1 = fmaf(A.y,  w1v[1], s1);
                s0 = fmaf(A.z,  w0[2], s0);  s1 = fmaf(A.z,  w1v[2], s1);
                s0 = fmaf(A.w,  w0[3], s0);  s1 = fmaf(A.w,  w1v[3], s1);
                s0 = fmaf(Bv.x, w0[4], s0);  s1 = fmaf(Bv.x, w1v[4], s1);
                s0 = fmaf(Bv.y, w0[5], s0);  s1 = fmaf(Bv.y, w1v[5], s1);
                s0 = fmaf(Bv.z, w0[6], s0);  s1 = fmaf(Bv.z, w1v[6], s1);
                a0[p] = s0; a1[p] = s1;
            }
        }
    }

    const float b0  = bias[oc];
    const float b1b = bias[oc + 64];
#pragma unroll
    for (int p = 0; p < 16; ++p) {
        int ow = ow0 + g * 16 + p;
        size_t ob = ((size_t)(bs * HH0 + oh) * WW0 + ow) * 128;
        out[ob + oc]      = fmaxf(a0[p] + b0, 0.0f);
        out[ob + oc + 64] = fmaxf(a1[p] + b1b, 0.0f);
    }
}

// ---------------------------------------------------------------------------
// Kernel 3: 3x3/s3 avg pool, channels-last
// ---------------------------------------------------------------------------
__global__ void pool_kernel(const float* __restrict__ in, float* __restrict__ out) {
    int idx = blockIdx.x * 256 + threadIdx.x;
    if (idx >= 4 * HH1 * WW1 * 128) return;
    int c = idx & 127;
    int r = idx >> 7;
    int px = r % WW1; r /= WW1;
    int py = r % HH1;
    int bs = r / HH1;
    float s = 0.0f;
#pragma unroll
    for (int dy = 0; dy < 3; ++dy)
#pragma unroll
        for (int dx = 0; dx < 3; ++dx)
            s += in[(((size_t)bs * HH0 + py * 3 + dy) * WW0 + px * 3 + dx) * 128 + c];
    out[idx] = s / 9.0f;
}

// ---------------------------------------------------------------------------
// Kernel 4: sample+corr. One wave per (point,map); 512 thr = 4 points.
// ---------------------------------------------------------------------------
__global__ __launch_bounds__(512) void sample_kernel(
    const float* __restrict__ fm, int hh, int ww,
    const float* __restrict__ cur_in, float* __restrict__ corr_out)
{
    __shared__ float smem[4 * 2400];
    const int tid  = threadIdx.x;
    const int wvi  = tid >> 6;                 // 0..7
    const int lane = tid & 63;
    const int ps   = wvi >> 1;                 // point slot 0..3
    const int mp   = wvi & 1;                  // map 0/1
    const int p    = blockIdx.x * 4 + ps;      // global point id
    const int b    = p >> 13;

    float* fl    = smem + ps * 2400;           // [9][132]
    float* ml    = fl + 1188;                  // [9][132]
    float* inv_s = fl + 2376;                  // [18]: 0..8 invf, 9..17 invm

    const float2 pxy = *(const float2*)(cur_in + (size_t)p * 2);
    const float wwm1 = (float)(ww - 1);
    const float hhm1 = (float)(hh - 1);
    const float ix = ((pxy.x * 2.0f - 1.0f) + 1.0f) * 0.5f * wwm1;
    const float iy = ((pxy.y * 2.0f - 1.0f) + 1.0f) * 0.5f * hhm1;
    const float x0 = floorf(ix), y0 = floorf(iy);
    const float fx1 = ix - x0, fx0 = 1.0f - fx1;
    const float fy1 = iy - y0, fy0 = 1.0f - fy1;

    int   cx[4], cy[4];
    float vx[4], vy[4];
#pragma unroll
    for (int j = 0; j < 4; ++j) {
        float xc = x0 + (float)(j - 1);
        vx[j] = (xc >= 0.0f && xc <= wwm1) ? 1.0f : 0.0f;
        cx[j] = (int)fminf(fmaxf(xc, 0.0f), wwm1);
        float yc = y0 + (float)(j - 1);
        vy[j] = (yc >= 0.0f && yc <= hhm1) ? 1.0f : 0.0f;
        cy[j] = (int)fminf(fmaxf(yc, 0.0f), hhm1);
    }
    float cwx[6], cwy[6];
#pragma unroll
    for (int t = 0; t < 3; ++t) {
        cwx[t * 2 + 0] = fx0 * vx[t]; cwx[t * 2 + 1] = fx1 * vx[t + 1];
        cwy[t * 2 + 0] = fy0 * vy[t]; cwy[t * 2 + 1] = fy1 * vy[t + 1];
    }

    // gather this wave's map: 4x4 float2 patch -> 9 window samples in LDS
    {
        const float2* src = (const float2*)fm + (size_t)(b * 2 + mp) * hh * ww * 64;
        float* dst = mp ? ml : fl;
        float2 P[4][4];
#pragma unroll
        for (int j = 0; j < 4; ++j)
#pragma unroll
            for (int i = 0; i < 4; ++i)
                P[j][i] = src[(cy[j] * ww + cx[i]) * 64 + lane];
#pragma unroll
        for (int ky = 0; ky < 3; ++ky)
#pragma unroll
            for (int kx = 0; kx < 3; ++kx) {
                float wA = cwy[ky * 2 + 0] * cwx[kx * 2 + 0];
                float wB = cwy[ky * 2 + 0] * cwx[kx * 2 + 1];
                float wC = cwy[ky * 2 + 1] * cwx[kx * 2 + 0];
                float wD = cwy[ky * 2 + 1] * cwx[kx * 2 + 1];
                float sx = wA * P[ky][kx].x;
                sx = fmaf(wB, P[ky][kx + 1].x, sx);
                sx = fmaf(wC, P[ky + 1][kx].x, sx);
                sx = fmaf(wD, P[ky + 1][kx + 1].x, sx);
                float sy = wA * P[ky][kx].y;
                sy = fmaf(wB, P[ky][kx + 1].y, sy);
                sy = fmaf(wC, P[ky + 1][kx].y, sy);
                sy = fmaf(wD, P[ky + 1][kx + 1].y, sy);
                *(float2*)(dst + (ky * 3 + kx) * 132 + 2 * lane) = make_float2(sx, sy);
            }
    }
    __syncthreads();

    // dots: this wave handles e = mp*64 + lane (0..98 valid)
    const int e = mp * 64 + lane;
    float s = 0.0f;
    {
        const float *rA, *rB;
        if (e < 81)      { rA = fl + (e / 9) * 132; rB = ml + (e % 9) * 132; }
        else if (e < 90) { rA = fl + (e - 81) * 132; rB = rA; }
        else             { int em = e - 90; if (em > 8) em = 8;
                           rA = ml + em * 132; rB = rA; }
#pragma unroll
        for (int c = 0; c < 128; c += 4) {
            float4 a  = *(const float4*)(rA + c);
            float4 bb = *(const float4*)(rB + c);
            s += a.x * bb.x; s += a.y * bb.y; s += a.z * bb.z; s += a.w * bb.w;
        }
    }
    if (e >= 81 && e < 90)      inv_s[e - 81]     = 1.0f / fmaxf(sqrtf(s), 1e-12f);
    else if (e >= 90 && e < 99) inv_s[e - 90 + 9] = 1.0f / fmaxf(sqrtf(s), 1e-12f);
    __syncthreads();

    if (e < 81)
        corr_out[(size_t)p * 81 + e] = s * inv_s[e / 9] * inv_s[9 + e % 9];
}

// ---------------------------------------------------------------------------
// Kernel 5: MLP + head. 16 points/block (1024 blocks). thread=(point, 16 j's).
// ---------------------------------------------------------------------------
__global__ __launch_bounds__(256) void mlp_kernel(
    const float* __restrict__ corr, const float* __restrict__ cur_in,
    const float* __restrict__ w1, const float* __restrict__ b1,
    const float* __restrict__ wp, const float* __restrict__ bp,
    const float* __restrict__ wvw, const float* __restrict__ bvv,
    int hh, int ww,
    float* __restrict__ cur_out,
    const float* __restrict__ vis_in, float* __restrict__ vis_out,
    int is_last)
{
    __shared__ float cls[16 * 81];    // corr rows for 16 points (linear copy)
    __shared__ float wps[256 * 9];    // wp
    __shared__ float wvs[256];        // wv
    __shared__ float red[4 * 10 * 16];
    const int tid   = threadIdx.x;
    const int wvi   = tid >> 6;
    const int lane  = tid & 63;
    const int pbase = blockIdx.x * 16;
    const int pl_   = lane & 15;              // point slot
    const int jg    = wvi * 4 + (lane >> 4);  // j-group 0..15
    const int j0    = jg * 16;

    // coalesced stages
    for (int idx = tid; idx < 16 * 81; idx += 256)
        cls[idx] = corr[(size_t)pbase * 81 + idx];
    for (int idx = tid; idx < 256 * 9; idx += 256)
        wps[idx] = wp[idx];
    if (tid < 256) wvs[tid] = wvw[tid];
    __syncthreads();

    float h[16];
#pragma unroll
    for (int jj = 0; jj < 16; ++jj) h[jj] = b1[j0 + jj];

    const float* crow = cls + pl_ * 81;
    for (int i = 0; i < 81; ++i) {
        const float cv = crow[i];
        const float4* wr = (const float4*)(w1 + i * 256 + j0);
        float4 w4a = wr[0], w4b = wr[1], w4c = wr[2], w4d = wr[3];
        h[0]  = fmaf(cv, w4a.x, h[0]);  h[1]  = fmaf(cv, w4a.y, h[1]);
        h[2]  = fmaf(cv, w4a.z, h[2]);  h[3]  = fmaf(cv, w4a.w, h[3]);
        h[4]  = fmaf(cv, w4b.x, h[4]);  h[5]  = fmaf(cv, w4b.y, h[5]);
        h[6]  = fmaf(cv, w4b.z, h[6]);  h[7]  = fmaf(cv, w4b.w, h[7]);
        h[8]  = fmaf(cv, w4c.x, h[8]);  h[9]  = fmaf(cv, w4c.y, h[9]);
        h[10] = fmaf(cv, w4c.z, h[10]); h[11] = fmaf(cv, w4c.w, h[11]);
        h[12] = fmaf(cv, w4d.x, h[12]); h[13] = fmaf(cv, w4d.y, h[13]);
        h[14] = fmaf(cv, w4d.z, h[14]); h[15] = fmaf(cv, w4d.w, h[15]);
    }

    float pl10[10];
#pragma unroll
    for (int o = 0; o < 10; ++o) pl10[o] = 0.0f;
#pragma unroll
    for (int jj = 0; jj < 16; ++jj) {
        float hv = fmaxf(h[jj], 0.0f);
        const float* wr = wps + (j0 + jj) * 9;
#pragma unroll
        for (int o = 0; o < 9; ++o) pl10[o] = fmaf(hv, wr[o], pl10[o]);
        pl10[9] = fmaf(hv, wvs[j0 + jj], pl10[9]);
    }
    // reduce across the 4 j-groups within the wave (lanes differing in bits 4,5)
#pragma unroll
    for (int o = 0; o < 10; ++o) {
        pl10[o] += __shfl_xor(pl10[o], 16);
        pl10[o] += __shfl_xor(pl10[o], 32);
    }
    if ((lane >> 4) == 0) {
#pragma unroll
        for (int o = 0; o < 10; ++o)
            red[(wvi * 10 + o) * 16 + pl_] = pl10[o];
    }
    __syncthreads();

    if (tid < 16) {
        const int p = pbase + tid;
        float fo[10];
#pragma unroll
        for (int o = 0; o < 10; ++o) {
            float v = red[o * 16 + tid];
            v += red[(10 + o) * 16 + tid];
            v += red[(20 + o) * 16 + tid];
            v += red[(30 + o) * 16 + tid];
            fo[o] = v;
        }
        float lg[9];
#pragma unroll
        for (int o = 0; o < 9; ++o) lg[o] = fo[o] + bp[o];
        float mx = lg[0];
#pragma unroll
        for (int o = 1; o < 9; ++o) mx = fmaxf(mx, lg[o]);
        float ex[9], sum = 0.0f;
#pragma unroll
        for (int o = 0; o < 9; ++o) { ex[o] = expf(lg[o] - mx); sum += ex[o]; }
#pragma unroll
        for (int o = 0; o < 9; ++o) ex[o] = ex[o] / sum;

        float vis = 1.0f / (1.0f + expf(-(fo[9] + bvv[0])));

        const float wwm1 = (float)(ww - 1);
        const float hhm1 = (float)(hh - 1);
        const float ax = 1.0f / wwm1;
        const float ay = 1.0f / hhm1;
        float r0 = ex[0] + ex[1] + ex[2];
        float r1 = ex[3] + ex[4] + ex[5];
        float r2 = ex[6] + ex[7] + ex[8];
        float c0 = ex[0] + ex[3] + ex[6];
        float c1 = ex[1] + ex[4] + ex[7];
        float c2 = ex[2] + ex[5] + ex[8];
        float dx = r0 * (-ax) + r1 * 0.0f + r2 * ax;
        float dy = c0 * (-ay) + c1 * 0.0f + c2 * ay;

        float2 pq = *(const float2*)(cur_in + (size_t)p * 2);
        *(float2*)(cur_out + (size_t)p * 2) = make_float2(pq.x + dx, pq.y + dy);
        vis_out[p] = is_last ? (vis_in[p] + vis) * 0.5f : vis;
    }
}

// ---------------------------------------------------------------------------
extern "C" void kernel_launch(void* const* d_in, const int* in_sizes, int n_in,
                              void* d_out, int out_size, void* d_ws, size_t ws_size,
                              hipStream_t stream) {
    (void)in_sizes; (void)n_in; (void)out_size; (void)ws_size;
    const float* queries = (const float*)d_in[0];
    const float* frames  = (const float*)d_in[1];
    const float* conv_w  = (const float*)d_in[2];
    const float* conv_b  = (const float*)d_in[3];
    const float* w1      = (const float*)d_in[4];
    const float* b1      = (const float*)d_in[5];
    const float* wp      = (const float*)d_in[6];
    const float* bp      = (const float*)d_in[7];
    const float* wvw     = (const float*)d_in[8];
    const float* bvv     = (const float*)d_in[9];
    float* out = (float*)d_out;

    // ws layout (floats): fm0 | fm1 | wT | cur_ws | vis_ws | corrws (~33.5 MB)
    float* ws     = (float*)d_ws;
    float* fm0    = ws;                         // 6291456
    float* fm1    = fm0 + 6291456;              // 688128
    float* wT     = fm1 + 688128;               // 18816
    float* cur_ws = wT + 18816;                 // 32768
    float* vis_ws = cur_ws + 32768;             // 16384
    float* corrws = vis_ws + 16384;             // 16384*81 = 1327104

    transpose_w_kernel<<<74, 256, 0, stream>>>(conv_w, wT);
    conv_kernel<<<dim3(2, HH0, 4), 256, 0, stream>>>(frames, wT, conv_b, fm0);
    pool_kernel<<<2688, 256, 0, stream>>>(fm0, fm1);

    // level 0: coarse map
    sample_kernel<<<4096, 512, 0, stream>>>(fm1, HH1, WW1, queries, corrws);
    mlp_kernel<<<1024, 256, 0, stream>>>(corrws, queries, w1, b1, wp, bp, wvw, bvv,
                                         HH1, WW1, cur_ws, nullptr, vis_ws, 0);
    // level 1: fine map, final outputs
    sample_kernel<<<4096, 512, 0, stream>>>(fm0, HH0, WW0, cur_ws, corrws);
    mlp_kernel<<<1024, 256, 0, stream>>>(corrws, cur_ws, w1, b1, wp, bp, wvw, bvv,
                                         HH0, WW0, out, vis_ws, out + 32768, 1);
}

// Round 4
// 265.379 us; speedup vs baseline: 1.2959x; 1.0159x over previous
//
#include <hip/hip_runtime.h>
#include <math.h>

// Problem constants
#define NQ 8192          // points per batch
#define NP 16384         // total points (B*NQ)
#define H_IN 384
#define W_IN 512
#define HH0 96           // conv out H
#define WW0 128          // conv out W
#define HH1 32           // pooled H
#define WW1 42           // pooled W

// ---------------------------------------------------------------------------
// Kernel 1: transpose conv weights (128,3,7,7) -> wT[tap][oc]
// ---------------------------------------------------------------------------
__global__ void transpose_w_kernel(const float* __restrict__ w, float* __restrict__ wT) {
    int idx = blockIdx.x * 256 + threadIdx.x;
    if (idx < 147 * 128) {
        int tap = idx >> 7;
        int oc  = idx & 127;
        wT[idx] = w[oc * 147 + tap];
    }
}

// ---------------------------------------------------------------------------
// Kernel 2: conv 7x7 stride 4 pad 3 + bias + relu, channels-last output
// ---------------------------------------------------------------------------
__global__ __launch_bounds__(256) void conv_kernel(
    const float* __restrict__ frames, const float* __restrict__ wT,
    const float* __restrict__ bias, float* __restrict__ out)
{
    __shared__ float lds[3 * 7 * 260];
    const int bs  = blockIdx.z;
    const int oh  = blockIdx.y;
    const int ow0 = blockIdx.x * 64;
    const int tid = threadIdx.x;

    for (int idx = tid; idx < 3 * 7 * 259; idx += 256) {
        int c   = idx / 1813;
        int rem = idx - c * 1813;
        int kh  = rem / 259;
        int col = rem - kh * 259;
        int gy  = oh * 4 - 3 + kh;
        int gx  = ow0 * 4 - 3 + col;
        float v = 0.0f;
        if (gy >= 0 && gy < H_IN && gx >= 0 && gx < W_IN) {
            float t = frames[((size_t)(bs * 3 + c) * H_IN + gy) * W_IN + gx];
            v = 2.0f * (t / 255.0f) - 1.0f;
        }
        lds[c * 1820 + kh * 260 + col] = v;
    }
    __syncthreads();

    const int oc = tid & 63;
    const int g  = tid >> 6;
    float a0[16], a1[16];
#pragma unroll
    for (int p = 0; p < 16; ++p) { a0[p] = 0.0f; a1[p] = 0.0f; }

#pragma unroll
    for (int c = 0; c < 3; ++c) {
#pragma unroll
        for (int kh = 0; kh < 7; ++kh) {
            const float* row = lds + c * 1820 + kh * 260 + g * 64;
            float w0[7], w1v[7];
#pragma unroll
            for (int kw = 0; kw < 7; ++kw) {
                int tap = (c * 7 + kh) * 7 + kw;
                w0[kw]  = wT[tap * 128 + oc];
                w1v[kw] = wT[tap * 128 + oc + 64];
            }
#pragma unroll
            for (int p = 0; p < 16; ++p) {
                const float4 A  = *(const float4*)(row + p * 4);
                const float4 Bv = *(const float4*)(row + p * 4 + 4);
                float s0 = a0[p], s1 = a1[p];
                s0 = fmaf(A.x,  w0[0], s0);  s1 = fmaf(A.x,  w1v[0], s1);
                s0 = fmaf(A.y,  w0[1], s0);  s1 = fmaf(A.y,  w1v[1], s1);
                s0 = fmaf(A.z,  w0[2], s0);  s1 = fmaf(A.z,  w1v[2], s1);
                s0 = fmaf(A.w,  w0[3], s0);  s1 = fmaf(A.w,  w1v[3], s1);
                s0 = fmaf(Bv.x, w0[4], s0);  s1 = fmaf(Bv.x, w1v[4], s1);
                s0 = fmaf(Bv.y, w0[5], s0);  s1 = fmaf(Bv.y, w1v[5], s1);
                s0 = fmaf(Bv.z, w0[6], s0);  s1 = fmaf(Bv.z, w1v[6], s1);
                a0[p] = s0; a1[p] = s1;
            }
        }
    }

    const float b0  = bias[oc];
    const float b1b = bias[oc + 64];
#pragma unroll
    for (int p = 0; p < 16; ++p) {
        int ow = ow0 + g * 16 + p;
        size_t ob = ((size_t)(bs * HH0 + oh) * WW0 + ow) * 128;
        out[ob + oc]      = fmaxf(a0[p] + b0, 0.0f);
        out[ob + oc + 64] = fmaxf(a1[p] + b1b, 0.0f);
    }
}

// ---------------------------------------------------------------------------
// Kernel 3: 3x3/s3 avg pool, channels-last
// ---------------------------------------------------------------------------
__global__ void pool_kernel(const float* __restrict__ in, float* __restrict__ out) {
    int idx = blockIdx.x * 256 + threadIdx.x;
    if (idx >= 4 * HH1 * WW1 * 128) return;
    int c = idx & 127;
    int r = idx >> 7;
    int px = r % WW1; r /= WW1;
    int py = r % HH1;
    int bs = r / HH1;
    float s = 0.0f;
#pragma unroll
    for (int dy = 0; dy < 3; ++dy)
#pragma unroll
        for (int dx = 0; dx < 3; ++dx)
            s += in[(((size_t)bs * HH0 + py * 3 + dy) * WW0 + px * 3 + dx) * 128 + c];
    out[idx] = s / 9.0f;
}

// ---------------------------------------------------------------------------
// Kernel 4: sample+corr. One wave per (point,map); 512 thr = 4 points.
// ---------------------------------------------------------------------------
__global__ __launch_bounds__(512) void sample_kernel(
    const float* __restrict__ fm, int hh, int ww,
    const float* __restrict__ cur_in, float* __restrict__ corr_out)
{
    __shared__ float smem[4 * 2400];
    const int tid  = threadIdx.x;
    const int wvi  = tid >> 6;                 // 0..7
    const int lane = tid & 63;
    const int ps   = wvi >> 1;                 // point slot 0..3
    const int mp   = wvi & 1;                  // map 0/1
    const int p    = blockIdx.x * 4 + ps;      // global point id
    const int b    = p >> 13;

    float* fl    = smem + ps * 2400;           // [9][132]
    float* ml    = fl + 1188;                  // [9][132]
    float* inv_s = fl + 2376;                  // [18]: 0..8 invf, 9..17 invm

    const float2 pxy = *(const float2*)(cur_in + (size_t)p * 2);
    const float wwm1 = (float)(ww - 1);
    const float hhm1 = (float)(hh - 1);
    const float ix = ((pxy.x * 2.0f - 1.0f) + 1.0f) * 0.5f * wwm1;
    const float iy = ((pxy.y * 2.0f - 1.0f) + 1.0f) * 0.5f * hhm1;
    const float x0 = floorf(ix), y0 = floorf(iy);
    const float fx1 = ix - x0, fx0 = 1.0f - fx1;
    const float fy1 = iy - y0, fy0 = 1.0f - fy1;

    int   cx[4], cy[4];
    float vx[4], vy[4];
#pragma unroll
    for (int j = 0; j < 4; ++j) {
        float xc = x0 + (float)(j - 1);
        vx[j] = (xc >= 0.0f && xc <= wwm1) ? 1.0f : 0.0f;
        cx[j] = (int)fminf(fmaxf(xc, 0.0f), wwm1);
        float yc = y0 + (float)(j - 1);
        vy[j] = (yc >= 0.0f && yc <= hhm1) ? 1.0f : 0.0f;
        cy[j] = (int)fminf(fmaxf(yc, 0.0f), hhm1);
    }
    float cwx[6], cwy[6];
#pragma unroll
    for (int t = 0; t < 3; ++t) {
        cwx[t * 2 + 0] = fx0 * vx[t]; cwx[t * 2 + 1] = fx1 * vx[t + 1];
        cwy[t * 2 + 0] = fy0 * vy[t]; cwy[t * 2 + 1] = fy1 * vy[t + 1];
    }

    // gather this wave's map: 4x4 float2 patch -> 9 window samples in LDS
    {
        const float2* src = (const float2*)fm + (size_t)(b * 2 + mp) * hh * ww * 64;
        float* dst = mp ? ml : fl;
        float2 P[4][4];
#pragma unroll
        for (int j = 0; j < 4; ++j)
#pragma unroll
            for (int i = 0; i < 4; ++i)
                P[j][i] = src[(cy[j] * ww + cx[i]) * 64 + lane];
#pragma unroll
        for (int ky = 0; ky < 3; ++ky)
#pragma unroll
            for (int kx = 0; kx < 3; ++kx) {
                float wA = cwy[ky * 2 + 0] * cwx[kx * 2 + 0];
                float wB = cwy[ky * 2 + 0] * cwx[kx * 2 + 1];
                float wC = cwy[ky * 2 + 1] * cwx[kx * 2 + 0];
                float wD = cwy[ky * 2 + 1] * cwx[kx * 2 + 1];
                float sx = wA * P[ky][kx].x;
                sx = fmaf(wB, P[ky][kx + 1].x, sx);
                sx = fmaf(wC, P[ky + 1][kx].x, sx);
                sx = fmaf(wD, P[ky + 1][kx + 1].x, sx);
                float sy = wA * P[ky][kx].y;
                sy = fmaf(wB, P[ky][kx + 1].y, sy);
                sy = fmaf(wC, P[ky + 1][kx].y, sy);
                sy = fmaf(wD, P[ky + 1][kx + 1].y, sy);
                *(float2*)(dst + (ky * 3 + kx) * 132 + 2 * lane) = make_float2(sx, sy);
            }
    }
    __syncthreads();

    // dots: this wave handles e = mp*64 + lane (0..98 valid)
    const int e = mp * 64 + lane;
    float s = 0.0f;
    {
        const float *rA, *rB;
        if (e < 81)      { rA = fl + (e / 9) * 132; rB = ml + (e % 9) * 132; }
        else if (e < 90) { rA = fl + (e - 81) * 132; rB = rA; }
        else             { int em = e - 90; if (em > 8) em = 8;
                           rA = ml + em * 132; rB = rA; }
#pragma unroll
        for (int c = 0; c < 128; c += 4) {
            float4 a  = *(const float4*)(rA + c);
            float4 bb = *(const float4*)(rB + c);
            s += a.x * bb.x; s += a.y * bb.y; s += a.z * bb.z; s += a.w * bb.w;
        }
    }
    if (e >= 81 && e < 90)      inv_s[e - 81]     = 1.0f / fmaxf(sqrtf(s), 1e-12f);
    else if (e >= 90 && e < 99) inv_s[e - 90 + 9] = 1.0f / fmaxf(sqrtf(s), 1e-12f);
    __syncthreads();

    if (e < 81)
        corr_out[(size_t)p * 81 + e] = s * inv_s[e / 9] * inv_s[9 + e % 9];
}

// ---------------------------------------------------------------------------
// Kernel 5: MLP + head. 8 points/block (2048 blocks).
// thread = (point pl_=lane&7, j-group jg = wvi*8 + (lane>>3), 8 j's each).
// i-loop hand-unrolled x3 with explicit prefetch for L2-latency pipelining.
// ---------------------------------------------------------------------------
__global__ __launch_bounds__(256) void mlp_kernel(
    const float* __restrict__ corr, const float* __restrict__ cur_in,
    const float* __restrict__ w1, const float* __restrict__ b1,
    const float* __restrict__ wp, const float* __restrict__ bp,
    const float* __restrict__ wvw, const float* __restrict__ bvv,
    int hh, int ww,
    float* __restrict__ cur_out,
    const float* __restrict__ vis_in, float* __restrict__ vis_out,
    int is_last)
{
    __shared__ float cls[8 * 81];     // corr rows for 8 points
    __shared__ float wps[256 * 9];    // wp
    __shared__ float wvs[256];        // wv
    __shared__ float red[4 * 10 * 8];
    const int tid   = threadIdx.x;
    const int wvi   = tid >> 6;
    const int lane  = tid & 63;
    const int pbase = blockIdx.x * 8;
    const int pl_   = lane & 7;               // point slot 0..7
    const int jg    = wvi * 8 + (lane >> 3);  // j-group 0..31
    const int j0    = jg * 8;

    // coalesced stages
    for (int idx = tid; idx < 8 * 81; idx += 256)
        cls[idx] = corr[(size_t)pbase * 81 + idx];
    for (int idx = tid; idx < 256 * 9; idx += 256)
        wps[idx] = wp[idx];
    if (tid < 256) wvs[tid] = wvw[tid];
    __syncthreads();

    float h[8];
    {
        const float4* bp4 = (const float4*)(b1 + j0);
        float4 h4a = bp4[0], h4b = bp4[1];
        h[0] = h4a.x; h[1] = h4a.y; h[2] = h4a.z; h[3] = h4a.w;
        h[4] = h4b.x; h[5] = h4b.y; h[6] = h4b.z; h[7] = h4b.w;
    }

    const float* crow = cls + pl_ * 81;
    // 81 = 27 * 3: unroll by 3, batch the 6 independent float4 loads first
    for (int i = 0; i < 81; i += 3) {
        const float cv0 = crow[i];
        const float cv1 = crow[i + 1];
        const float cv2 = crow[i + 2];
        const float4* wr0 = (const float4*)(w1 + (i    ) * 256 + j0);
        const float4* wr1 = (const float4*)(w1 + (i + 1) * 256 + j0);
        const float4* wr2 = (const float4*)(w1 + (i + 2) * 256 + j0);
        const float4 a0 = wr0[0], a1 = wr0[1];
        const float4 b0 = wr1[0], b1v = wr1[1];
        const float4 c0 = wr2[0], c1 = wr2[1];
        h[0] = fmaf(cv0, a0.x, h[0]); h[1] = fmaf(cv0, a0.y, h[1]);
        h[2] = fmaf(cv0, a0.z, h[2]); h[3] = fmaf(cv0, a0.w, h[3]);
        h[4] = fmaf(cv0, a1.x, h[4]); h[5] = fmaf(cv0, a1.y, h[5]);
        h[6] = fmaf(cv0, a1.z, h[6]); h[7] = fmaf(cv0, a1.w, h[7]);
        h[0] = fmaf(cv1, b0.x, h[0]); h[1] = fmaf(cv1, b0.y, h[1]);
        h[2] = fmaf(cv1, b0.z, h[2]); h[3] = fmaf(cv1, b0.w, h[3]);
        h[4] = fmaf(cv1, b1v.x, h[4]); h[5] = fmaf(cv1, b1v.y, h[5]);
        h[6] = fmaf(cv1, b1v.z, h[6]); h[7] = fmaf(cv1, b1v.w, h[7]);
        h[0] = fmaf(cv2, c0.x, h[0]); h[1] = fmaf(cv2, c0.y, h[1]);
        h[2] = fmaf(cv2, c0.z, h[2]); h[3] = fmaf(cv2, c0.w, h[3]);
        h[4] = fmaf(cv2, c1.x, h[4]); h[5] = fmaf(cv2, c1.y, h[5]);
        h[6] = fmaf(cv2, c1.z, h[6]); h[7] = fmaf(cv2, c1.w, h[7]);
    }

    float pl10[10];
#pragma unroll
    for (int o = 0; o < 10; ++o) pl10[o] = 0.0f;
#pragma unroll
    for (int jj = 0; jj < 8; ++jj) {
        float hv = fmaxf(h[jj], 0.0f);
        const float* wr = wps + (j0 + jj) * 9;
#pragma unroll
        for (int o = 0; o < 9; ++o) pl10[o] = fmaf(hv, wr[o], pl10[o]);
        pl10[9] = fmaf(hv, wvs[j0 + jj], pl10[9]);
    }
    // reduce across the 8 j-groups within the wave (lane bits 3,4,5)
#pragma unroll
    for (int o = 0; o < 10; ++o) {
        pl10[o] += __shfl_xor(pl10[o], 8);
        pl10[o] += __shfl_xor(pl10[o], 16);
        pl10[o] += __shfl_xor(pl10[o], 32);
    }
    if ((lane >> 3) == 0) {
#pragma unroll
        for (int o = 0; o < 10; ++o)
            red[(wvi * 10 + o) * 8 + pl_] = pl10[o];
    }
    __syncthreads();

    if (tid < 8) {
        const int p = pbase + tid;
        float fo[10];
#pragma unroll
        for (int o = 0; o < 10; ++o) {
            float v = red[o * 8 + tid];
            v += red[(10 + o) * 8 + tid];
            v += red[(20 + o) * 8 + tid];
            v += red[(30 + o) * 8 + tid];
            fo[o] = v;
        }
        float lg[9];
#pragma unroll
        for (int o = 0; o < 9; ++o) lg[o] = fo[o] + bp[o];
        float mx = lg[0];
#pragma unroll
        for (int o = 1; o < 9; ++o) mx = fmaxf(mx, lg[o]);
        float ex[9], sum = 0.0f;
#pragma unroll
        for (int o = 0; o < 9; ++o) { ex[o] = expf(lg[o] - mx); sum += ex[o]; }
#pragma unroll
        for (int o = 0; o < 9; ++o) ex[o] = ex[o] / sum;

        float vis = 1.0f / (1.0f + expf(-(fo[9] + bvv[0])));

        const float wwm1 = (float)(ww - 1);
        const float hhm1 = (float)(hh - 1);
        const float ax = 1.0f / wwm1;
        const float ay = 1.0f / hhm1;
        float r0 = ex[0] + ex[1] + ex[2];
        float r1 = ex[3] + ex[4] + ex[5];
        float r2 = ex[6] + ex[7] + ex[8];
        float c0 = ex[0] + ex[3] + ex[6];
        float c1 = ex[1] + ex[4] + ex[7];
        float c2 = ex[2] + ex[5] + ex[8];
        float dx = r0 * (-ax) + r1 * 0.0f + r2 * ax;
        float dy = c0 * (-ay) + c1 * 0.0f + c2 * ay;

        float2 pq = *(const float2*)(cur_in + (size_t)p * 2);
        *(float2*)(cur_out + (size_t)p * 2) = make_float2(pq.x + dx, pq.y + dy);
        vis_out[p] = is_last ? (vis_in[p] + vis) * 0.5f : vis;
    }
}

// ---------------------------------------------------------------------------
extern "C" void kernel_launch(void* const* d_in, const int* in_sizes, int n_in,
                              void* d_out, int out_size, void* d_ws, size_t ws_size,
                              hipStream_t stream) {
    (void)in_sizes; (void)n_in; (void)out_size; (void)ws_size;
    const float* queries = (const float*)d_in[0];
    const float* frames  = (const float*)d_in[1];
    const float* conv_w  = (const float*)d_in[2];
    const float* conv_b  = (const float*)d_in[3];
    const float* w1      = (const float*)d_in[4];
    const float* b1      = (const float*)d_in[5];
    const float* wp      = (const float*)d_in[6];
    const float* bp      = (const float*)d_in[7];
    const float* wvw     = (const float*)d_in[8];
    const float* bvv     = (const float*)d_in[9];
    float* out = (float*)d_out;

    // ws layout (floats): fm0 | fm1 | wT | cur_ws | vis_ws | corrws (~33.5 MB)
    float* ws     = (float*)d_ws;
    float* fm0    = ws;                         // 6291456
    float* fm1    = fm0 + 6291456;              // 688128
    float* wT     = fm1 + 688128;               // 18816
    float* cur_ws = wT + 18816;                 // 32768
    float* vis_ws = cur_ws + 32768;             // 16384
    float* corrws = vis_ws + 16384;             // 16384*81 = 1327104

    transpose_w_kernel<<<74, 256, 0, stream>>>(conv_w, wT);
    conv_kernel<<<dim3(2, HH0, 4), 256, 0, stream>>>(frames, wT, conv_b, fm0);
    pool_kernel<<<2688, 256, 0, stream>>>(fm0, fm1);

    // level 0: coarse map
    sample_kernel<<<4096, 512, 0, stream>>>(fm1, HH1, WW1, queries, corrws);
    mlp_kernel<<<2048, 256, 0, stream>>>(corrws, queries, w1, b1, wp, bp, wvw, bvv,
                                         HH1, WW1, cur_ws, nullptr, vis_ws, 0);
    // level 1: fine map, final outputs
    sample_kernel<<<4096, 512, 0, stream>>>(fm0, HH0, WW0, cur_ws, corrws);
    mlp_kernel<<<2048, 256, 0, stream>>>(corrws, cur_ws, w1, b1, wp, bp, wvw, bvv,
                                         HH0, WW0, out, vis_ws, out + 32768, 1);
}